// Round 1
// baseline (332.906 us; speedup 1.0000x reference)
//
#include <hip/hip_runtime.h>
#include <cstdint>

typedef unsigned short u16;
typedef __bf16 bf16;
typedef bf16 bf16x8 __attribute__((ext_vector_type(8)));
typedef u16 u16x4 __attribute__((ext_vector_type(4)));
typedef u16 u16x8 __attribute__((ext_vector_type(8)));
typedef float f32x4 __attribute__((ext_vector_type(4)));

__device__ __forceinline__ u16 f2b(float f) {
    return __builtin_bit_cast(u16, (bf16)f);
}
__device__ __forceinline__ float b2f(u16 u) {
    return __uint_as_float(((unsigned)u) << 16);
}
__device__ __forceinline__ void load_lds16(const void* g, void* l) {
    auto gp = reinterpret_cast<const __attribute__((address_space(1))) void*>(
        reinterpret_cast<uintptr_t>(g));
    auto lp = reinterpret_cast<__attribute__((address_space(3))) void*>(
        reinterpret_cast<uintptr_t>(l));
    __builtin_amdgcn_global_load_lds(gp, lp, 16, 0, 0);
}
__device__ __forceinline__ f32x4 mfma16(bf16x8 a, bf16x8 b, f32x4 c) {
    return __builtin_amdgcn_mfma_f32_16x16x32_bf16(a, b, c, 0, 0, 0);
}

// ---------------------------------------------------------------- convert x -> bf16
__global__ __launch_bounds__(256) void convx_kernel(const float* __restrict__ x,
                                                    u16* __restrict__ xb, int n4) {
    int i = blockIdx.x * blockDim.x + threadIdx.x;
    int stride = gridDim.x * blockDim.x;
    for (; i < n4; i += stride) {
        float4 v = ((const float4*)x)[i];
        u16x4 r;
        r[0] = f2b(v.x); r[1] = f2b(v.y); r[2] = f2b(v.z); r[3] = f2b(v.w);
        *(u16x4*)&xb[(size_t)i * 4] = r;
    }
}

// ------------------------------------------------- transpose+convert w [K][N] f32 -> wT [N][K] bf16
__global__ __launch_bounds__(256) void wtrans_kernel(const float* __restrict__ w,
                                                     u16* __restrict__ wT, int K, int N) {
    __shared__ float tile[32][33];
    int tx = threadIdx.x, ty = threadIdx.y;  // (32, 8)
    int n0 = blockIdx.x * 32, k0 = blockIdx.y * 32;
#pragma unroll
    for (int i = 0; i < 4; ++i)
        tile[ty + i * 8][tx] = w[(size_t)(k0 + ty + i * 8) * N + n0 + tx];
    __syncthreads();
#pragma unroll
    for (int i = 0; i < 4; ++i)
        wT[(size_t)(n0 + ty + i * 8) * K + k0 + tx] = f2b(tile[tx][ty + i * 8]);
}

// ---------------------------------------------------------------- GEMM: C[M][N] = A[M][K] * Bt[N][K]^T + bias
// A, Bt bf16 row-major (ld = K). 128x128 tile, 4 waves (2x2), 16x16x32 MFMA,
// global_load_lds staging with XOR slot swizzle (swizzle applied on global src + LDS read).
template <bool OUT_BF16>
__global__ __launch_bounds__(256, 2) void gemm_kernel(const u16* __restrict__ A,
                                                      const u16* __restrict__ Bt,
                                                      const float* __restrict__ bias,
                                                      void* __restrict__ out,
                                                      int M, int N, int K) {
    __shared__ __align__(16) u16 As[128 * 64];
    __shared__ __align__(16) u16 Bs[128 * 64];
    const int tid = threadIdx.x;
    const int wave = tid >> 6, lane = tid & 63;
    const int l15 = lane & 15, lg = lane >> 4;
    const int tm = blockIdx.y * 128, tn = blockIdx.x * 128;
    const int wr = (wave >> 1) * 64, wc = (wave & 1) * 64;

    f32x4 acc[4][4] = {};

    // staging constants: inst i covers rows i*32 + wave*8 + lane/8, phys slot lane%8.
    const int rbase = wave * 8 + (lane >> 3);
    const int sslot = (lane & 7) ^ (rbase & 7);          // logical slot to fetch
    const u16* gA = A + (size_t)(tm + rbase) * K + sslot * 8;
    const u16* gB = Bt + (size_t)(tn + rbase) * K + sslot * 8;
    u16* ldsA = As + (size_t)(wave * 8) * 64;
    u16* ldsB = Bs + (size_t)(wave * 8) * 64;

    for (int kt = 0; kt < K; kt += 64) {
#pragma unroll
        for (int i = 0; i < 4; ++i) {
            load_lds16(gA + (size_t)i * 32 * K + kt, ldsA + i * 32 * 64);
            load_lds16(gB + (size_t)i * 32 * K + kt, ldsB + i * 32 * 64);
        }
        __syncthreads();  // drains vmcnt for gload_lds
#pragma unroll
        for (int kk = 0; kk < 64; kk += 32) {
            const int sb = kk >> 3;  // 0 or 4
            bf16x8 af[4], bfr[4];
#pragma unroll
            for (int m = 0; m < 4; ++m) {
                int row = wr + m * 16 + l15;
                int phys = (sb + lg) ^ (row & 7);
                af[m] = *(const bf16x8*)&As[row * 64 + phys * 8];
            }
#pragma unroll
            for (int n = 0; n < 4; ++n) {
                int row = wc + n * 16 + l15;
                int phys = (sb + lg) ^ (row & 7);
                bfr[n] = *(const bf16x8*)&Bs[row * 64 + phys * 8];
            }
#pragma unroll
            for (int m = 0; m < 4; ++m)
#pragma unroll
                for (int n = 0; n < 4; ++n)
                    acc[m][n] = mfma16(af[m], bfr[n], acc[m][n]);
        }
        __syncthreads();
    }

    // epilogue: C row = tm+wr+m*16+lg*4+r, col = tn+wc+n*16+l15
#pragma unroll
    for (int n = 0; n < 4; ++n) {
        int col = tn + wc + n * 16 + l15;
        float bv = bias[col];
#pragma unroll
        for (int m = 0; m < 4; ++m) {
            int row0 = tm + wr + m * 16 + lg * 4;
#pragma unroll
            for (int r = 0; r < 4; ++r) {
                float v = acc[m][n][r] + bv;
                if constexpr (OUT_BF16)
                    ((u16*)out)[(size_t)(row0 + r) * N + col] = f2b(v);
                else
                    ((float*)out)[(size_t)(row0 + r) * N + col] = v;
            }
        }
    }
}

// ---------------------------------------------------------------- V transpose: qkv V-part -> vt[bh][d=64][s=2048]
__global__ __launch_bounds__(256) void vtrans_kernel(const u16* __restrict__ qkv,
                                                     u16* __restrict__ vt) {
    __shared__ __align__(16) u16 tile[64][72];
    const int st = blockIdx.x, bh = blockIdx.y;
    const int b = bh / 12, h = bh % 12;
    const int t = threadIdx.x;
    const int sr = t >> 2, c4 = (t & 3) * 16;
    const u16* src = qkv + (size_t)(b * 2048 + st * 64 + sr) * 2304 + 1536 + h * 64 + c4;
    *(u16x8*)&tile[sr][c4] = *(const u16x8*)src;
    *(u16x8*)&tile[sr][c4 + 8] = *(const u16x8*)(src + 8);
    __syncthreads();
    const int dr = t >> 2, s4 = (t & 3) * 16;
    u16x8 w0, w1;
#pragma unroll
    for (int j = 0; j < 8; ++j) {
        w0[j] = tile[s4 + j][dr];
        w1[j] = tile[s4 + 8 + j][dr];
    }
    u16* dst = vt + ((size_t)bh * 64 + dr) * 2048 + st * 64 + s4;
    *(u16x8*)dst = w0;
    *(u16x8*)(dst + 8) = w1;
}

// ---------------------------------------------------------------- per-128-tile V column sums: ts[bh][16][64]
__global__ __launch_bounds__(256) void tilesum_kernel(const u16* __restrict__ qkv,
                                                      float* __restrict__ ts) {
    const int t = blockIdx.x, bh = blockIdx.y;
    const int b = bh / 12, h = bh % 12;
    const int tid = threadIdx.x;
    const int d = tid & 63, rg = tid >> 6;
    float s = 0.f;
    const u16* base = qkv + (size_t)(b * 2048 + t * 128 + rg * 32) * 2304 + 1536 + h * 64 + d;
#pragma unroll 4
    for (int i = 0; i < 32; ++i) s += b2f(base[(size_t)i * 2304]);
    __shared__ float red[256];
    red[tid] = s;
    __syncthreads();
    if (tid < 64)
        ts[((size_t)bh * 16 + t) * 64 + d] =
            red[tid] + red[tid + 64] + red[tid + 128] + red[tid + 192];
}

// ---------------------------------------------------------------- attention
// grid (qt=16, bh=48), 256 thr (4 waves). QBLK=128 (32 q-rows/wave), KBLK=64.
// Causal tiles only; diagonal tiles masked to 1e-9; analytic future-tail correction.
__global__ __launch_bounds__(256, 2) void attn_kernel(const u16* __restrict__ qkv,
                                                      const u16* __restrict__ vt,
                                                      const float* __restrict__ ts,
                                                      u16* __restrict__ aout) {
    __shared__ __align__(16) u16 Ks[64 * 64];
    __shared__ __align__(16) u16 Vs[64 * 64];   // transposed V: [d][k]
    __shared__ __align__(16) u16 Ps[128 * 64];
    const int qt = blockIdx.x, bh = blockIdx.y;
    const int b = bh / 12, h = bh % 12;
    const int tid = threadIdx.x, wave = tid >> 6, lane = tid & 63;
    const int l15 = lane & 15, lg = lane >> 4;
    const int q0 = qt * 128 + wave * 32;       // wave's first q (seq index)
    const size_t rowbase = (size_t)b * 2048;

    // Q fragments in registers: aq[m][ks]
    bf16x8 aq[2][2];
#pragma unroll
    for (int m = 0; m < 2; ++m)
#pragma unroll
        for (int ks = 0; ks < 2; ++ks)
            aq[m][ks] = *(const bf16x8*)(qkv + (rowbase + q0 + m * 16 + l15) * 2304 +
                                         h * 64 + ks * 32 + lg * 8);

    f32x4 o[2][4] = {};
    float mrun[2][4], lrun[2][4];
#pragma unroll
    for (int m = 0; m < 2; ++m)
#pragma unroll
        for (int r = 0; r < 4; ++r) { mrun[m][r] = -1e30f; lrun[m][r] = 0.f; }

    // staging constants
    const int rbase = wave * 8 + (lane >> 3);
    const int sslot = (lane & 7) ^ (rbase & 7);
    const u16* gK = qkv + (rowbase + rbase) * 2304 + 768 + h * 64 + sslot * 8;
    const u16* gV = vt + ((size_t)bh * 64 + rbase) * 2048 + sslot * 8;
    u16* ldsK = Ks + (size_t)(wave * 8) * 64;
    u16* ldsV = Vs + (size_t)(wave * 8) * 64;

    const int nkt = 2 * qt + 2;
    for (int kt = 0; kt < nkt; ++kt) {
#pragma unroll
        for (int i = 0; i < 2; ++i) {
            load_lds16(gK + (size_t)(kt * 64 + i * 32) * 2304, ldsK + i * 32 * 64);
            load_lds16(gV + (size_t)(i * 32) * 2048 + kt * 64, ldsV + i * 32 * 64);
        }
        __syncthreads();

        // S = Q K^T for this tile
        f32x4 sacc[2][4] = {};
#pragma unroll
        for (int ks = 0; ks < 2; ++ks) {
            const int sb = ks * 4;
            bf16x8 bk[4];
#pragma unroll
            for (int n = 0; n < 4; ++n) {
                int row = n * 16 + l15;
                bk[n] = *(const bf16x8*)&Ks[row * 64 + ((sb + lg) ^ (row & 7)) * 8];
            }
#pragma unroll
            for (int m = 0; m < 2; ++m)
#pragma unroll
                for (int n = 0; n < 4; ++n)
                    sacc[m][n] = mfma16(aq[m][ks], bk[n], sacc[m][n]);
        }

        // reference mask trick on diagonal tiles: masked score := 1e-9
        if (kt >= 2 * qt) {
#pragma unroll
            for (int m = 0; m < 2; ++m)
#pragma unroll
                for (int n = 0; n < 4; ++n)
#pragma unroll
                    for (int r = 0; r < 4; ++r) {
                        int q = q0 + m * 16 + lg * 4 + r;
                        int k = kt * 64 + n * 16 + l15;
                        if (k > q) sacc[m][n][r] = 1e-9f;
                    }
        }

        // online softmax (row stats via 16-lane shfl_xor reduction)
#pragma unroll
        for (int m = 0; m < 2; ++m) {
#pragma unroll
            for (int r = 0; r < 4; ++r) {
                float mx = fmaxf(fmaxf(sacc[m][0][r], sacc[m][1][r]),
                                 fmaxf(sacc[m][2][r], sacc[m][3][r]));
                mx = fmaxf(mx, __shfl_xor(mx, 1));
                mx = fmaxf(mx, __shfl_xor(mx, 2));
                mx = fmaxf(mx, __shfl_xor(mx, 4));
                mx = fmaxf(mx, __shfl_xor(mx, 8));
                float mold = mrun[m][r];
                float mnew = fmaxf(mold, mx);
                float alpha = __expf(mold - mnew);
                mrun[m][r] = mnew;
                float rs = 0.f;
#pragma unroll
                for (int n = 0; n < 4; ++n) {
                    float p = __expf(sacc[m][n][r] - mnew);
                    sacc[m][n][r] = p;
                    rs += p;
                }
                rs += __shfl_xor(rs, 1);
                rs += __shfl_xor(rs, 2);
                rs += __shfl_xor(rs, 4);
                rs += __shfl_xor(rs, 8);
                lrun[m][r] = lrun[m][r] * alpha + rs;
#pragma unroll
                for (int dn = 0; dn < 4; ++dn) o[m][dn][r] *= alpha;
            }
        }

        // write P (bf16, swizzled) to LDS
#pragma unroll
        for (int m = 0; m < 2; ++m)
#pragma unroll
            for (int n = 0; n < 4; ++n)
#pragma unroll
                for (int r = 0; r < 4; ++r) {
                    int ql = wave * 32 + m * 16 + lg * 4 + r;
                    int kl = n * 16 + l15;
                    Ps[ql * 64 + (((kl >> 3) ^ (ql & 7)) << 3) + (kl & 7)] =
                        f2b(sacc[m][n][r]);
                }
        __syncthreads();

        // O += P * V
#pragma unroll
        for (int ks = 0; ks < 2; ++ks) {
            const int sb = ks * 4;
            bf16x8 ap[2];
#pragma unroll
            for (int m = 0; m < 2; ++m) {
                int row = wave * 32 + m * 16 + l15;
                ap[m] = *(const bf16x8*)&Ps[row * 64 + ((sb + lg) ^ (row & 7)) * 8];
            }
#pragma unroll
            for (int dn = 0; dn < 4; ++dn) {
                int row = dn * 16 + l15;
                bf16x8 bv = *(const bf16x8*)&Vs[row * 64 + ((sb + lg) ^ (row & 7)) * 8];
#pragma unroll
                for (int m = 0; m < 2; ++m) o[m][dn] = mfma16(ap[m], bv, o[m][dn]);
            }
        }
        __syncthreads();
    }

    // analytic future tail: all k >= (qt+1)*128 carry score exactly 1e-9
    const int nf = 2048 - (qt + 1) * 128;
    if (nf > 0) {
        float carr[2][4], aarr[2][4];
#pragma unroll
        for (int m = 0; m < 2; ++m)
#pragma unroll
            for (int r = 0; r < 4; ++r) {
                float mold = mrun[m][r];
                float mnew = fmaxf(mold, 1e-9f);
                aarr[m][r] = __expf(mold - mnew);
                carr[m][r] = __expf(1e-9f - mnew);
                lrun[m][r] = lrun[m][r] * aarr[m][r] + (float)nf * carr[m][r];
            }
#pragma unroll
        for (int dn = 0; dn < 4; ++dn) {
            float suf = 0.f;
            for (int t = qt + 1; t < 16; ++t)
                suf += ts[((size_t)bh * 16 + t) * 64 + dn * 16 + l15];
#pragma unroll
            for (int m = 0; m < 2; ++m)
#pragma unroll
                for (int r = 0; r < 4; ++r)
                    o[m][dn][r] = o[m][dn][r] * aarr[m][r] + carr[m][r] * suf;
        }
    }

    // normalize + store merged-head layout [B*S][768] bf16
#pragma unroll
    for (int m = 0; m < 2; ++m)
#pragma unroll
        for (int r = 0; r < 4; ++r) {
            float inv = 1.f / lrun[m][r];
            size_t row = rowbase + q0 + m * 16 + lg * 4 + r;
#pragma unroll
            for (int dn = 0; dn < 4; ++dn)
                aout[row * 768 + h * 64 + dn * 16 + l15] = f2b(o[m][dn][r] * inv);
        }
}

// ---------------------------------------------------------------- launch
extern "C" void kernel_launch(void* const* d_in, const int* in_sizes, int n_in,
                              void* d_out, int out_size, void* d_ws, size_t ws_size,
                              hipStream_t stream) {
    const float* x      = (const float*)d_in[0];
    const float* w_attn = (const float*)d_in[1];
    const float* b_attn = (const float*)d_in[2];
    const float* w_proj = (const float*)d_in[3];
    const float* b_proj = (const float*)d_in[4];
    float* out = (float*)d_out;
    char* ws = (char*)d_ws;

    u16* xb    = (u16*)(ws + 0);          // 8192*768   bf16 = 12,582,912 B
    u16* wTa   = (u16*)(ws + 12582912);   // 2304*768   bf16 =  3,538,944 B
    u16* wTp   = (u16*)(ws + 16121856);   //  768*768   bf16 =  1,179,648 B
    u16* qkv   = (u16*)(ws + 17301504);   // 8192*2304  bf16 = 37,748,736 B
    u16* vt    = (u16*)(ws + 55050240);   // 48*64*2048 bf16 = 12,582,912 B
    float* ts  = (float*)(ws + 67633152); // 48*16*64   f32  =    196,608 B
    u16* aout  = (u16*)(ws + 67829760);   // 8192*768   bf16 = 12,582,912 B
    // total ws use: 80,412,672 B

    convx_kernel<<<dim3(2048), dim3(256), 0, stream>>>(x, xb, 8192 * 768 / 4);
    wtrans_kernel<<<dim3(72, 24), dim3(32, 8), 0, stream>>>(w_attn, wTa, 768, 2304);
    wtrans_kernel<<<dim3(24, 24), dim3(32, 8), 0, stream>>>(w_proj, wTp, 768, 768);
    gemm_kernel<true><<<dim3(18, 64), dim3(256), 0, stream>>>(xb, wTa, b_attn,
                                                              (void*)qkv, 8192, 2304, 768);
    vtrans_kernel<<<dim3(32, 48), dim3(256), 0, stream>>>(qkv, vt);
    tilesum_kernel<<<dim3(16, 48), dim3(256), 0, stream>>>(qkv, ts);
    attn_kernel<<<dim3(16, 48), dim3(256), 0, stream>>>(qkv, vt, ts, aout);
    gemm_kernel<false><<<dim3(6, 64), dim3(256), 0, stream>>>(aout, wTp, b_proj,
                                                              (void*)out, 8192, 768, 768);
}

// Round 2
// 254.653 us; speedup vs baseline: 1.3073x; 1.3073x over previous
//
#include <hip/hip_runtime.h>
#include <cstdint>

typedef unsigned short u16;
typedef __bf16 bf16;
typedef bf16 bf16x8 __attribute__((ext_vector_type(8)));
typedef u16 u16x4 __attribute__((ext_vector_type(4)));
typedef u16 u16x8 __attribute__((ext_vector_type(8)));
typedef float f32x4 __attribute__((ext_vector_type(4)));

__device__ __forceinline__ u16 f2b(float f) {
    return __builtin_bit_cast(u16, (bf16)f);
}
__device__ __forceinline__ float b2f(u16 u) {
    return __uint_as_float(((unsigned)u) << 16);
}
__device__ __forceinline__ void load_lds16(const void* g, void* l) {
    auto gp = reinterpret_cast<const __attribute__((address_space(1))) void*>(
        reinterpret_cast<uintptr_t>(g));
    auto lp = reinterpret_cast<__attribute__((address_space(3))) void*>(
        reinterpret_cast<uintptr_t>(l));
    __builtin_amdgcn_global_load_lds(gp, lp, 16, 0, 0);
}
__device__ __forceinline__ f32x4 mfma16(bf16x8 a, bf16x8 b, f32x4 c) {
    return __builtin_amdgcn_mfma_f32_16x16x32_bf16(a, b, c, 0, 0, 0);
}

// ---------------------------------------------------------------- convert x -> bf16
__global__ __launch_bounds__(256) void convx_kernel(const float* __restrict__ x,
                                                    u16* __restrict__ xb, int n4) {
    int i = blockIdx.x * blockDim.x + threadIdx.x;
    int stride = gridDim.x * blockDim.x;
    for (; i < n4; i += stride) {
        float4 v = ((const float4*)x)[i];
        u16x4 r;
        r[0] = f2b(v.x); r[1] = f2b(v.y); r[2] = f2b(v.z); r[3] = f2b(v.w);
        *(u16x4*)&xb[(size_t)i * 4] = r;
    }
}

// ------------------------------------------------- transpose+convert w [K][N] f32 -> wT [N][K] bf16
__global__ __launch_bounds__(256) void wtrans_kernel(const float* __restrict__ w,
                                                     u16* __restrict__ wT, int K, int N) {
    __shared__ float tile[32][33];
    int tx = threadIdx.x, ty = threadIdx.y;  // (32, 8)
    int n0 = blockIdx.x * 32, k0 = blockIdx.y * 32;
#pragma unroll
    for (int i = 0; i < 4; ++i)
        tile[ty + i * 8][tx] = w[(size_t)(k0 + ty + i * 8) * N + n0 + tx];
    __syncthreads();
#pragma unroll
    for (int i = 0; i < 4; ++i)
        wT[(size_t)(n0 + ty + i * 8) * K + k0 + tx] = f2b(tile[tx][ty + i * 8]);
}

// ---------------------------------------------------------------- GEMM: C[M][N] = A[M][K] * Bt[N][K]^T + bias
template <bool OUT_BF16>
__global__ __launch_bounds__(256, 2) void gemm_kernel(const u16* __restrict__ A,
                                                      const u16* __restrict__ Bt,
                                                      const float* __restrict__ bias,
                                                      void* __restrict__ out,
                                                      int M, int N, int K) {
    __shared__ __align__(16) u16 As[128 * 64];
    __shared__ __align__(16) u16 Bs[128 * 64];
    const int tid = threadIdx.x;
    const int wave = tid >> 6, lane = tid & 63;
    const int l15 = lane & 15, lg = lane >> 4;
    const int tm = blockIdx.y * 128, tn = blockIdx.x * 128;
    const int wr = (wave >> 1) * 64, wc = (wave & 1) * 64;

    f32x4 acc[4][4] = {};

    const int rbase = wave * 8 + (lane >> 3);
    const int sslot = (lane & 7) ^ (rbase & 7);
    const u16* gA = A + (size_t)(tm + rbase) * K + sslot * 8;
    const u16* gB = Bt + (size_t)(tn + rbase) * K + sslot * 8;
    u16* ldsA = As + (size_t)(wave * 8) * 64;
    u16* ldsB = Bs + (size_t)(wave * 8) * 64;

    for (int kt = 0; kt < K; kt += 64) {
#pragma unroll
        for (int i = 0; i < 4; ++i) {
            load_lds16(gA + (size_t)i * 32 * K + kt, ldsA + i * 32 * 64);
            load_lds16(gB + (size_t)i * 32 * K + kt, ldsB + i * 32 * 64);
        }
        __syncthreads();
#pragma unroll
        for (int kk = 0; kk < 64; kk += 32) {
            const int sb = kk >> 3;
            bf16x8 af[4], bfr[4];
#pragma unroll
            for (int m = 0; m < 4; ++m) {
                int row = wr + m * 16 + l15;
                af[m] = *(const bf16x8*)&As[row * 64 + (((sb + lg) ^ (row & 7))) * 8];
            }
#pragma unroll
            for (int n = 0; n < 4; ++n) {
                int row = wc + n * 16 + l15;
                bfr[n] = *(const bf16x8*)&Bs[row * 64 + (((sb + lg) ^ (row & 7))) * 8];
            }
#pragma unroll
            for (int m = 0; m < 4; ++m)
#pragma unroll
                for (int n = 0; n < 4; ++n)
                    acc[m][n] = mfma16(af[m], bfr[n], acc[m][n]);
        }
        __syncthreads();
    }

#pragma unroll
    for (int n = 0; n < 4; ++n) {
        int col = tn + wc + n * 16 + l15;
        float bv = bias[col];
#pragma unroll
        for (int m = 0; m < 4; ++m) {
            int row0 = tm + wr + m * 16 + lg * 4;
#pragma unroll
            for (int r = 0; r < 4; ++r) {
                float v = acc[m][n][r] + bv;
                if constexpr (OUT_BF16)
                    ((u16*)out)[(size_t)(row0 + r) * N + col] = f2b(v);
                else
                    ((float*)out)[(size_t)(row0 + r) * N + col] = v;
            }
        }
    }
}

// ---------------------------------------------------------------- V transpose: qkv V-part -> vt[bh][d=64][s=2048]
__global__ __launch_bounds__(256) void vtrans_kernel(const u16* __restrict__ qkv,
                                                     u16* __restrict__ vt) {
    __shared__ __align__(16) u16 tile[64][72];
    const int st = blockIdx.x, bh = blockIdx.y;
    const int b = bh / 12, h = bh % 12;
    const int t = threadIdx.x;
    const int sr = t >> 2, c4 = (t & 3) * 16;
    const u16* src = qkv + (size_t)(b * 2048 + st * 64 + sr) * 2304 + 1536 + h * 64 + c4;
    *(u16x8*)&tile[sr][c4] = *(const u16x8*)src;
    *(u16x8*)&tile[sr][c4 + 8] = *(const u16x8*)(src + 8);
    __syncthreads();
    const int dr = t >> 2, s4 = (t & 3) * 16;
    u16x8 w0, w1;
#pragma unroll
    for (int j = 0; j < 8; ++j) {
        w0[j] = tile[s4 + j][dr];
        w1[j] = tile[s4 + 8 + j][dr];
    }
    u16* dst = vt + ((size_t)bh * 64 + dr) * 2048 + st * 64 + s4;
    *(u16x8*)dst = w0;
    *(u16x8*)(dst + 8) = w1;
}

// ---------------------------------------------------------------- per-64-tile V column sums: ts_raw[bh][32][64]
__global__ __launch_bounds__(256) void tilesum_kernel(const u16* __restrict__ qkv,
                                                      float* __restrict__ ts_raw) {
    const int t = blockIdx.x, bh = blockIdx.y;
    const int b = bh / 12, h = bh % 12;
    const int tid = threadIdx.x;
    const int d = tid & 63, rg = tid >> 6;
    float s = 0.f;
    const u16* base = qkv + (size_t)(b * 2048 + t * 64 + rg * 16) * 2304 + 1536 + h * 64 + d;
#pragma unroll 4
    for (int i = 0; i < 16; ++i) s += b2f(base[(size_t)i * 2304]);
    __shared__ float red[256];
    red[tid] = s;
    __syncthreads();
    if (tid < 64)
        ts_raw[((size_t)bh * 32 + t) * 64 + d] =
            red[tid] + red[tid + 64] + red[tid + 128] + red[tid + 192];
}

// ---------------------------------------------------------------- suffix sums: ts_suf[bh][t][d] = sum_{t'>=t} ts_raw
__global__ __launch_bounds__(64) void suffix_kernel(const float* __restrict__ ts_raw,
                                                    float* __restrict__ ts_suf) {
    const int bh = blockIdx.x, d = threadIdx.x;
    float acc = 0.f;
    for (int t = 31; t >= 0; --t) {
        acc += ts_raw[((size_t)bh * 32 + t) * 64 + d];
        ts_suf[((size_t)bh * 32 + t) * 64 + d] = acc;
    }
}

// ---------------------------------------------------------------- attention (swapped-operand, S^T/O^T layout)
// grid (32 qt, 48 bh), 256 thr (4 waves). QBLK=64 (16 q-rows/wave), KBLK=64.
// One barrier/iter; K/V double-buffered; each lane owns one q-row (k lane-local).
__global__ __launch_bounds__(256, 4) void attn_kernel(const u16* __restrict__ qkv,
                                                      const u16* __restrict__ vt,
                                                      const float* __restrict__ ts_suf,
                                                      u16* __restrict__ aout) {
    __shared__ __align__(16) u16 Ks[2][64 * 64];
    __shared__ __align__(16) u16 Vs[2][64 * 64];   // transposed V: [d][k]
    __shared__ __align__(16) u16 Ps[64 * 64];      // P rows [q_local][k], per-wave private rows
    const int qt = 31 - blockIdx.x, bh = blockIdx.y;   // longest blocks first
    const int b = bh / 12, h = bh % 12;
    const int tid = threadIdx.x, wave = tid >> 6, lane = tid & 63;
    const int l15 = lane & 15, lg = lane >> 4;
    const int q0 = qt * 64 + wave * 16;
    const size_t rowbase = (size_t)b * 2048;

    // Q fragment (B-operand): lane holds Q[q0+l15][ks*32 + lg*8 .. +8]
    bf16x8 qf[2];
#pragma unroll
    for (int ks = 0; ks < 2; ++ks)
        qf[ks] = *(const bf16x8*)(qkv + (rowbase + q0 + l15) * 2304 + h * 64 +
                                  ks * 32 + lg * 8);

    f32x4 o[4] = {};          // O^T: lane holds O[q=q0+l15][d = dn*16 + lg*4 + r]
    float mrun = -1e30f, lrun = 0.f;

    // staging constants (gload_lds: linear LDS dest, pre-swizzled global source)
    const int rbase = wave * 8 + (lane >> 3);
    const int sslot = (lane & 7) ^ (rbase & 7);
    const u16* gK = qkv + (rowbase + rbase) * 2304 + 768 + h * 64 + sslot * 8;
    const u16* gV = vt + ((size_t)bh * 64 + rbase) * 2048 + sslot * 8;
    const int ldsoff = wave * 8 * 64;

    const int nkt = qt + 1;
    // prologue: stage kt=0 into buffer 0
#pragma unroll
    for (int i = 0; i < 2; ++i) {
        load_lds16(gK + (size_t)(i * 32) * 2304, &Ks[0][ldsoff + i * 32 * 64]);
        load_lds16(gV + (size_t)(i * 32) * 2048, &Vs[0][ldsoff + i * 32 * 64]);
    }

    for (int kt = 0; kt < nkt; ++kt) {
        __syncthreads();  // implicit vmcnt(0)+lgkmcnt(0): tile[cur] ready, prev reads done
        const int cur = kt & 1;
        if (kt + 1 < nkt) {
            const int nx = cur ^ 1;
#pragma unroll
            for (int i = 0; i < 2; ++i) {
                load_lds16(gK + ((size_t)(kt + 1) * 64 + i * 32) * 2304,
                           &Ks[nx][ldsoff + i * 32 * 64]);
                load_lds16(gV + (size_t)(i * 32) * 2048 + (kt + 1) * 64,
                           &Vs[nx][ldsoff + i * 32 * 64]);
            }
        }

        // S^T = K Q^T : lane gets S[k = kt*64 + n*16 + lg*4 + r][q = q0 + l15]
        f32x4 sacc[4] = {};
#pragma unroll
        for (int ks = 0; ks < 2; ++ks) {
#pragma unroll
            for (int n = 0; n < 4; ++n) {
                int row = n * 16 + l15;
                bf16x8 ak = *(const bf16x8*)&Ks[cur][row * 64 +
                                                     (((ks * 4 + lg) ^ (row & 7))) * 8];
                sacc[n] = mfma16(ak, qf[ks], sacc[n]);
            }
        }

        // reference mask trick on the diagonal tile
        if (kt == qt) {
            const int q = q0 + l15;
#pragma unroll
            for (int n = 0; n < 4; ++n)
#pragma unroll
                for (int r = 0; r < 4; ++r) {
                    int k = kt * 64 + n * 16 + lg * 4 + r;
                    if (k > q) sacc[n][r] = 1e-9f;
                }
        }

        // online softmax: row is lane-local (16 regs) + 2 shfl to fold lane-groups
        float mx = sacc[0][0];
#pragma unroll
        for (int n = 0; n < 4; ++n)
#pragma unroll
            for (int r = 0; r < 4; ++r) mx = fmaxf(mx, sacc[n][r]);
        mx = fmaxf(mx, __shfl_xor(mx, 16));
        mx = fmaxf(mx, __shfl_xor(mx, 32));
        const float mnew = fmaxf(mrun, mx);
        const float alpha = __expf(mrun - mnew);
        mrun = mnew;
        float rs = 0.f;
        u16x4 pk[4];
#pragma unroll
        for (int n = 0; n < 4; ++n)
#pragma unroll
            for (int r = 0; r < 4; ++r) {
                float p = __expf(sacc[n][r] - mnew);
                rs += p;
                pk[n][r] = f2b(p);
            }
        rs += __shfl_xor(rs, 16);
        rs += __shfl_xor(rs, 32);
        lrun = lrun * alpha + rs;
#pragma unroll
        for (int dn = 0; dn < 4; ++dn) o[dn] *= alpha;

        // write P^T fragments -> Ps[q_local][k] (b64, swizzled); rows are wave-private
        const int prow = wave * 16 + l15;
#pragma unroll
        for (int n = 0; n < 4; ++n) {
            int slot = n * 2 + (lg >> 1);
            *(u16x4*)&Ps[prow * 64 + ((slot ^ (prow & 7))) * 8 + (lg & 1) * 4] = pk[n];
        }

        // O^T += V^T P^T
#pragma unroll
        for (int ks = 0; ks < 2; ++ks) {
            bf16x8 bp = *(const bf16x8*)&Ps[prow * 64 +
                                            (((ks * 4 + lg) ^ (prow & 7))) * 8];
#pragma unroll
            for (int dn = 0; dn < 4; ++dn) {
                int row = dn * 16 + l15;
                bf16x8 av = *(const bf16x8*)&Vs[cur][row * 64 +
                                                     (((ks * 4 + lg) ^ (row & 7))) * 8];
                o[dn] = mfma16(av, bp, o[dn]);
            }
        }
    }

    // analytic future tail: all k >= (qt+1)*64 carry score exactly 1e-9
    if (qt < 31) {
        const float nf = (float)((31 - qt) * 64);
        const float mnew = fmaxf(mrun, 1e-9f);
        const float a = __expf(mrun - mnew);
        const float c = __expf(1e-9f - mnew);
        lrun = lrun * a + nf * c;
        const float* sufp = ts_suf + ((size_t)bh * 32 + qt + 1) * 64;
#pragma unroll
        for (int dn = 0; dn < 4; ++dn) {
            f32x4 suf = *(const f32x4*)&sufp[dn * 16 + lg * 4];
            o[dn] = o[dn] * a + suf * c;
        }
    }

    // normalize + store merged-head layout [B*S][768] bf16 (lane-aligned with stats)
    const float inv = 1.f / lrun;
    const size_t row = rowbase + q0 + l15;
#pragma unroll
    for (int dn = 0; dn < 4; ++dn) {
        u16x4 st;
#pragma unroll
        for (int r = 0; r < 4; ++r) st[r] = f2b(o[dn][r] * inv);
        *(u16x4*)&aout[row * 768 + h * 64 + dn * 16 + lg * 4] = st;
    }
}

// ---------------------------------------------------------------- launch
extern "C" void kernel_launch(void* const* d_in, const int* in_sizes, int n_in,
                              void* d_out, int out_size, void* d_ws, size_t ws_size,
                              hipStream_t stream) {
    const float* x      = (const float*)d_in[0];
    const float* w_attn = (const float*)d_in[1];
    const float* b_attn = (const float*)d_in[2];
    const float* w_proj = (const float*)d_in[3];
    const float* b_proj = (const float*)d_in[4];
    float* out = (float*)d_out;
    char* ws = (char*)d_ws;

    u16* xb      = (u16*)(ws + 0);          // 8192*768   bf16 = 12,582,912 B
    u16* wTa     = (u16*)(ws + 12582912);   // 2304*768   bf16 =  3,538,944 B
    u16* wTp     = (u16*)(ws + 16121856);   //  768*768   bf16 =  1,179,648 B
    u16* qkv     = (u16*)(ws + 17301504);   // 8192*2304  bf16 = 37,748,736 B
    u16* vt      = (u16*)(ws + 55050240);   // 48*64*2048 bf16 = 12,582,912 B
    u16* aout    = (u16*)(ws + 67633152);   // 8192*768   bf16 = 12,582,912 B
    // ts buffers reuse the xb region (xb's last consumer is gemm1, which runs first)
    float* ts_raw = (float*)(ws + 0);       // 48*32*64 f32 = 393,216 B (aliases xb)
    float* ts_suf = (float*)(ws + 393216);  // 48*32*64 f32 = 393,216 B (aliases xb)
    // high-water: 80,216,064 B

    convx_kernel<<<dim3(2048), dim3(256), 0, stream>>>(x, xb, 8192 * 768 / 4);
    wtrans_kernel<<<dim3(72, 24), dim3(32, 8), 0, stream>>>(w_attn, wTa, 768, 2304);
    wtrans_kernel<<<dim3(24, 24), dim3(32, 8), 0, stream>>>(w_proj, wTp, 768, 768);
    gemm_kernel<true><<<dim3(18, 64), dim3(256), 0, stream>>>(xb, wTa, b_attn,
                                                              (void*)qkv, 8192, 2304, 768);
    vtrans_kernel<<<dim3(32, 48), dim3(256), 0, stream>>>(qkv, vt);
    tilesum_kernel<<<dim3(32, 48), dim3(256), 0, stream>>>(qkv, ts_raw);
    suffix_kernel<<<dim3(48), dim3(64), 0, stream>>>(ts_raw, ts_suf);
    attn_kernel<<<dim3(32, 48), dim3(256), 0, stream>>>(qkv, vt, ts_suf, aout);
    gemm_kernel<false><<<dim3(6, 64), dim3(256), 0, stream>>>(aout, wTp, b_proj,
                                                              (void*)out, 8192, 768, 768);
}

// Round 3
// 208.614 us; speedup vs baseline: 1.5958x; 1.2207x over previous
//
#include <hip/hip_runtime.h>
#include <cstdint>

typedef unsigned short u16;
typedef __bf16 bf16;
typedef bf16 bf16x8 __attribute__((ext_vector_type(8)));
typedef u16 u16x4 __attribute__((ext_vector_type(4)));
typedef u16 u16x8 __attribute__((ext_vector_type(8)));
typedef float f32x4 __attribute__((ext_vector_type(4)));

__device__ __forceinline__ u16 f2b(float f) {
    return __builtin_bit_cast(u16, (bf16)f);
}
__device__ __forceinline__ float b2f(u16 u) {
    return __uint_as_float(((unsigned)u) << 16);
}
__device__ __forceinline__ void load_lds16(const void* g, void* l) {
    auto gp = reinterpret_cast<const __attribute__((address_space(1))) void*>(
        reinterpret_cast<uintptr_t>(g));
    auto lp = reinterpret_cast<__attribute__((address_space(3))) void*>(
        reinterpret_cast<uintptr_t>(l));
    __builtin_amdgcn_global_load_lds(gp, lp, 16, 0, 0);
}
__device__ __forceinline__ f32x4 mfma16(bf16x8 a, bf16x8 b, f32x4 c) {
    return __builtin_amdgcn_mfma_f32_16x16x32_bf16(a, b, c, 0, 0, 0);
}

// ---------------------------------------------------------------- convert x -> bf16
__global__ __launch_bounds__(256) void convx_kernel(const float* __restrict__ x,
                                                    u16* __restrict__ xb, int n4) {
    int i = blockIdx.x * blockDim.x + threadIdx.x;
    int stride = gridDim.x * blockDim.x;
    for (; i < n4; i += stride) {
        float4 v = ((const float4*)x)[i];
        u16x4 r;
        r[0] = f2b(v.x); r[1] = f2b(v.y); r[2] = f2b(v.z); r[3] = f2b(v.w);
        *(u16x4*)&xb[(size_t)i * 4] = r;
    }
}

// ------------------------------------------------- transpose+convert w [K][N] f32 -> wT [N][K] bf16
__global__ __launch_bounds__(256) void wtrans_kernel(const float* __restrict__ w,
                                                     u16* __restrict__ wT, int K, int N) {
    __shared__ float tile[32][33];
    int tx = threadIdx.x, ty = threadIdx.y;  // (32, 8)
    int n0 = blockIdx.x * 32, k0 = blockIdx.y * 32;
#pragma unroll
    for (int i = 0; i < 4; ++i)
        tile[ty + i * 8][tx] = w[(size_t)(k0 + ty + i * 8) * N + n0 + tx];
    __syncthreads();
#pragma unroll
    for (int i = 0; i < 4; ++i)
        wT[(size_t)(n0 + ty + i * 8) * K + k0 + tx] = f2b(tile[tx][ty + i * 8]);
}

// ---------------------------------------------------------------- GEMM: C[M][N] = A[M][K] * Bt[N][K]^T + bias
// 128x128 tile, 4 waves, 16x16x32 MFMA, gload_lds staging, XCD-aware block swizzle.
template <bool OUT_BF16>
__global__ __launch_bounds__(256, 2) void gemm_kernel(const u16* __restrict__ A,
                                                      const u16* __restrict__ Bt,
                                                      const float* __restrict__ bias,
                                                      void* __restrict__ out,
                                                      int M, int N, int K) {
    __shared__ __align__(16) u16 As[128 * 64];
    __shared__ __align__(16) u16 Bs[128 * 64];
    const int tid = threadIdx.x;
    const int wave = tid >> 6, lane = tid & 63;
    const int l15 = lane & 15, lg = lane >> 4;
    // XCD-aware swizzle (T1); nwg % 8 == 0 for both GEMMs here.
    const int gx = gridDim.x;
    const int nwg = gx * gridDim.y;
    const int lin = blockIdx.y * gx + blockIdx.x;
    const int swz = (lin & 7) * (nwg >> 3) + (lin >> 3);
    const int tm = (swz / gx) * 128, tn = (swz % gx) * 128;
    const int wr = (wave >> 1) * 64, wc = (wave & 1) * 64;

    f32x4 acc[4][4] = {};

    const int rbase = wave * 8 + (lane >> 3);
    const int sslot = (lane & 7) ^ (rbase & 7);
    const u16* gA = A + (size_t)(tm + rbase) * K + sslot * 8;
    const u16* gB = Bt + (size_t)(tn + rbase) * K + sslot * 8;
    u16* ldsA = As + (size_t)(wave * 8) * 64;
    u16* ldsB = Bs + (size_t)(wave * 8) * 64;

    for (int kt = 0; kt < K; kt += 64) {
#pragma unroll
        for (int i = 0; i < 4; ++i) {
            load_lds16(gA + (size_t)i * 32 * K + kt, ldsA + i * 32 * 64);
            load_lds16(gB + (size_t)i * 32 * K + kt, ldsB + i * 32 * 64);
        }
        __syncthreads();
#pragma unroll
        for (int kk = 0; kk < 64; kk += 32) {
            const int sb = kk >> 3;
            bf16x8 af[4], bfr[4];
#pragma unroll
            for (int m = 0; m < 4; ++m) {
                int row = wr + m * 16 + l15;
                af[m] = *(const bf16x8*)&As[row * 64 + (((sb + lg) ^ (row & 7))) * 8];
            }
#pragma unroll
            for (int n = 0; n < 4; ++n) {
                int row = wc + n * 16 + l15;
                bfr[n] = *(const bf16x8*)&Bs[row * 64 + (((sb + lg) ^ (row & 7))) * 8];
            }
#pragma unroll
            for (int m = 0; m < 4; ++m)
#pragma unroll
                for (int n = 0; n < 4; ++n)
                    acc[m][n] = mfma16(af[m], bfr[n], acc[m][n]);
        }
        __syncthreads();
    }

#pragma unroll
    for (int n = 0; n < 4; ++n) {
        int col = tn + wc + n * 16 + l15;
        float bv = bias[col];
#pragma unroll
        for (int m = 0; m < 4; ++m) {
            int row0 = tm + wr + m * 16 + lg * 4;
#pragma unroll
            for (int r = 0; r < 4; ++r) {
                float v = acc[m][n][r] + bv;
                if constexpr (OUT_BF16)
                    ((u16*)out)[(size_t)(row0 + r) * N + col] = f2b(v);
                else
                    ((float*)out)[(size_t)(row0 + r) * N + col] = v;
            }
        }
    }
}

// ---------------------------------------------------------------- V transpose + fused per-64-tile colsum
// qkv V-part -> vt[bh][d=64][s=2048]; ts_raw[bh][st][d] = sum_s V[st*64+s][d]
__global__ __launch_bounds__(256) void vtrans_kernel(const u16* __restrict__ qkv,
                                                     u16* __restrict__ vt,
                                                     float* __restrict__ ts_raw) {
    __shared__ __align__(16) u16 tile[64][72];
    __shared__ float red2[64][4];
    const int st = blockIdx.x, bh = blockIdx.y;
    const int b = bh / 12, h = bh % 12;
    const int t = threadIdx.x;
    const int sr = t >> 2, c4 = (t & 3) * 16;
    const u16* src = qkv + (size_t)(b * 2048 + st * 64 + sr) * 2304 + 1536 + h * 64 + c4;
    *(u16x8*)&tile[sr][c4] = *(const u16x8*)src;
    *(u16x8*)&tile[sr][c4 + 8] = *(const u16x8*)(src + 8);
    __syncthreads();
    const int dr = t >> 2, s4 = (t & 3) * 16;
    u16x8 w0, w1;
    float psum = 0.f;
#pragma unroll
    for (int j = 0; j < 8; ++j) {
        w0[j] = tile[s4 + j][dr];
        w1[j] = tile[s4 + 8 + j][dr];
        psum += b2f(w0[j]) + b2f(w1[j]);
    }
    u16* dst = vt + ((size_t)bh * 64 + dr) * 2048 + st * 64 + s4;
    *(u16x8*)dst = w0;
    *(u16x8*)(dst + 8) = w1;
    red2[dr][t & 3] = psum;
    __syncthreads();
    if (t < 64)
        ts_raw[((size_t)bh * 32 + st) * 64 + t] =
            red2[t][0] + red2[t][1] + red2[t][2] + red2[t][3];
}

// ---------------------------------------------------------------- suffix sums: ts_suf[bh][t][d] = sum_{t'>=t} ts_raw
__global__ __launch_bounds__(64) void suffix_kernel(const float* __restrict__ ts_raw,
                                                    float* __restrict__ ts_suf) {
    const int bh = blockIdx.x, d = threadIdx.x;
    float acc = 0.f;
    for (int t = 31; t >= 0; --t) {
        acc += ts_raw[((size_t)bh * 32 + t) * 64 + d];
        ts_suf[((size_t)bh * 32 + t) * 64 + d] = acc;
    }
}

// ---------------------------------------------------------------- attention (swapped-operand, defer-max)
// grid (48 bh, 32 qtr), 256 thr (4 waves). QBLK=64 (16 q-rows/wave), KBLK=64.
// One barrier/iter; K/V double-buffered; defer-max keeps the common path shuffle-free.
__global__ __launch_bounds__(256, 4) void attn_kernel(const u16* __restrict__ qkv,
                                                      const u16* __restrict__ vt,
                                                      const float* __restrict__ ts_suf,
                                                      u16* __restrict__ aout) {
    __shared__ __align__(16) u16 Ks[2][64 * 64];
    __shared__ __align__(16) u16 Vs[2][64 * 64];   // transposed V: [d][k]
    __shared__ __align__(16) u16 Ps[64 * 64];      // P^T rows [q_local][k], wave-private rows
    const int bh = blockIdx.x;                     // bh fastest: same-bh blocks share XCD L2
    const int qt = 31 - blockIdx.y;                // longest-first dispatch
    const int b = bh / 12, h = bh % 12;
    const int tid = threadIdx.x, wave = tid >> 6, lane = tid & 63;
    const int l15 = lane & 15, lg = lane >> 4;
    const int q0 = qt * 64 + wave * 16;
    const size_t rowbase = (size_t)b * 2048;

    // Q fragment (B-operand): lane holds Q[q0+l15][ks*32 + lg*8 .. +8]
    bf16x8 qf[2];
#pragma unroll
    for (int ks = 0; ks < 2; ++ks)
        qf[ks] = *(const bf16x8*)(qkv + (rowbase + q0 + l15) * 2304 + h * 64 +
                                  ks * 32 + lg * 8);

    f32x4 o[4] = {};          // O^T: lane holds O[q=q0+l15][d = dn*16 + lg*4 + r]
    float mrun = -1e30f;
    float lrun = 0.f;         // per-lane partial (this lane's k subset); folded after loop

    // staging constants (gload_lds: linear LDS dest, pre-swizzled global source)
    const int rbase = wave * 8 + (lane >> 3);
    const int sslot = (lane & 7) ^ (rbase & 7);
    const u16* gK = qkv + (rowbase + rbase) * 2304 + 768 + h * 64 + sslot * 8;
    const u16* gV = vt + ((size_t)bh * 64 + rbase) * 2048 + sslot * 8;
    const int ldsoff = wave * 8 * 64;

    const int nkt = qt + 1;
#pragma unroll
    for (int i = 0; i < 2; ++i) {
        load_lds16(gK + (size_t)(i * 32) * 2304, &Ks[0][ldsoff + i * 32 * 64]);
        load_lds16(gV + (size_t)(i * 32) * 2048, &Vs[0][ldsoff + i * 32 * 64]);
    }

    for (int kt = 0; kt < nkt; ++kt) {
        __syncthreads();  // drains vmcnt: tile[cur] ready; prev-iter LDS reads done
        const int cur = kt & 1;
        if (kt + 1 < nkt) {
            const int nx = cur ^ 1;
#pragma unroll
            for (int i = 0; i < 2; ++i) {
                load_lds16(gK + ((size_t)(kt + 1) * 64 + i * 32) * 2304,
                           &Ks[nx][ldsoff + i * 32 * 64]);
                load_lds16(gV + (size_t)(i * 32) * 2048 + (kt + 1) * 64,
                           &Vs[nx][ldsoff + i * 32 * 64]);
            }
        }

        // S^T = K Q^T : lane gets S[k = kt*64 + n*16 + lg*4 + r][q = q0 + l15]
        f32x4 sacc[4] = {};
        __builtin_amdgcn_s_setprio(1);
#pragma unroll
        for (int ks = 0; ks < 2; ++ks) {
#pragma unroll
            for (int n = 0; n < 4; ++n) {
                int row = n * 16 + l15;
                bf16x8 ak = *(const bf16x8*)&Ks[cur][row * 64 +
                                                     (((ks * 4 + lg) ^ (row & 7))) * 8];
                sacc[n] = mfma16(ak, qf[ks], sacc[n]);
            }
        }
        __builtin_amdgcn_s_setprio(0);

        // reference mask trick on the diagonal tile
        if (kt == qt) {
            const int q = q0 + l15;
#pragma unroll
            for (int n = 0; n < 4; ++n)
#pragma unroll
                for (int r = 0; r < 4; ++r) {
                    int k = kt * 64 + n * 16 + lg * 4 + r;
                    if (k > q) sacc[n][r] = 1e-9f;
                }
        }

        // defer-max online softmax: lane-local max; rescale only when it grows >THR
        float mx = fmaxf(fmaxf(sacc[0][0], sacc[0][1]), fmaxf(sacc[0][2], sacc[0][3]));
#pragma unroll
        for (int n = 1; n < 4; ++n)
            mx = fmaxf(mx, fmaxf(fmaxf(sacc[n][0], sacc[n][1]),
                                 fmaxf(sacc[n][2], sacc[n][3])));
        if (__any(mx > mrun + 8.0f)) {
            float rm = fmaxf(mx, __shfl_xor(mx, 16));
            rm = fmaxf(rm, __shfl_xor(rm, 32));
            const float mnew = fmaxf(mrun, rm);
            const float alpha = __expf(mrun - mnew);
            mrun = mnew;
            lrun *= alpha;
#pragma unroll
            for (int dn = 0; dn < 4; ++dn) o[dn] *= alpha;
        }

        u16x4 pk[4];
#pragma unroll
        for (int n = 0; n < 4; ++n)
#pragma unroll
            for (int r = 0; r < 4; ++r) {
                float p = __expf(sacc[n][r] - mrun);   // bounded by e^8
                lrun += p;
                pk[n][r] = f2b(p);
            }

        // write P^T fragments -> Ps[q_local][k] (b64, swizzled); rows are wave-private
        const int prow = wave * 16 + l15;
#pragma unroll
        for (int n = 0; n < 4; ++n) {
            int slot = n * 2 + (lg >> 1);
            *(u16x4*)&Ps[prow * 64 + ((slot ^ (prow & 7))) * 8 + (lg & 1) * 4] = pk[n];
        }

        // O^T += V^T P^T
        __builtin_amdgcn_s_setprio(1);
#pragma unroll
        for (int ks = 0; ks < 2; ++ks) {
            bf16x8 bp = *(const bf16x8*)&Ps[prow * 64 +
                                            (((ks * 4 + lg) ^ (prow & 7))) * 8];
#pragma unroll
            for (int dn = 0; dn < 4; ++dn) {
                int row = dn * 16 + l15;
                bf16x8 av = *(const bf16x8*)&Vs[cur][row * 64 +
                                                     (((ks * 4 + lg) ^ (row & 7))) * 8];
                o[dn] = mfma16(av, bp, o[dn]);
            }
        }
        __builtin_amdgcn_s_setprio(0);
    }

    // fold per-lane l across the 4 lane-groups of this row (once, not per tile)
    lrun += __shfl_xor(lrun, 16);
    lrun += __shfl_xor(lrun, 32);

    // analytic future tail: all k >= (qt+1)*64 carry score exactly 1e-9
    if (qt < 31) {
        const float nf = (float)((31 - qt) * 64);
        const float mnew = fmaxf(mrun, 1e-9f);
        const float a = __expf(mrun - mnew);
        const float c = __expf(1e-9f - mnew);
        lrun = lrun * a + nf * c;
        const float* sufp = ts_suf + ((size_t)bh * 32 + qt + 1) * 64;
#pragma unroll
        for (int dn = 0; dn < 4; ++dn) {
            f32x4 suf = *(const f32x4*)&sufp[dn * 16 + lg * 4];
            o[dn] = o[dn] * a + suf * c;
        }
    }

    // normalize + store merged-head layout [B*S][768] bf16
    const float inv = 1.f / lrun;
    const size_t row = rowbase + q0 + l15;
#pragma unroll
    for (int dn = 0; dn < 4; ++dn) {
        u16x4 st;
#pragma unroll
        for (int r = 0; r < 4; ++r) st[r] = f2b(o[dn][r] * inv);
        *(u16x4*)&aout[row * 768 + h * 64 + dn * 16 + lg * 4] = st;
    }
}

// ---------------------------------------------------------------- launch
extern "C" void kernel_launch(void* const* d_in, const int* in_sizes, int n_in,
                              void* d_out, int out_size, void* d_ws, size_t ws_size,
                              hipStream_t stream) {
    const float* x      = (const float*)d_in[0];
    const float* w_attn = (const float*)d_in[1];
    const float* b_attn = (const float*)d_in[2];
    const float* w_proj = (const float*)d_in[3];
    const float* b_proj = (const float*)d_in[4];
    float* out = (float*)d_out;
    char* ws = (char*)d_ws;

    u16* xb      = (u16*)(ws + 0);          // 8192*768   bf16 = 12,582,912 B
    u16* wTa     = (u16*)(ws + 12582912);   // 2304*768   bf16 =  3,538,944 B
    u16* wTp     = (u16*)(ws + 16121856);   //  768*768   bf16 =  1,179,648 B
    u16* qkv     = (u16*)(ws + 17301504);   // 8192*2304  bf16 = 37,748,736 B
    u16* vt      = (u16*)(ws + 55050240);   // 48*64*2048 bf16 = 12,582,912 B
    u16* aout    = (u16*)(ws + 67633152);   // 8192*768   bf16 = 12,582,912 B
    // ts buffers reuse the xb region (xb's last consumer is gemm1, which runs earlier)
    float* ts_raw = (float*)(ws + 0);       // 48*32*64 f32 = 393,216 B (aliases xb)
    float* ts_suf = (float*)(ws + 393216);  // 48*32*64 f32 = 393,216 B (aliases xb)

    convx_kernel<<<dim3(2048), dim3(256), 0, stream>>>(x, xb, 8192 * 768 / 4);
    wtrans_kernel<<<dim3(72, 24), dim3(32, 8), 0, stream>>>(w_attn, wTa, 768, 2304);
    wtrans_kernel<<<dim3(24, 24), dim3(32, 8), 0, stream>>>(w_proj, wTp, 768, 768);
    gemm_kernel<true><<<dim3(18, 64), dim3(256), 0, stream>>>(xb, wTa, b_attn,
                                                              (void*)qkv, 8192, 2304, 768);
    vtrans_kernel<<<dim3(32, 48), dim3(256), 0, stream>>>(qkv, vt, ts_raw);
    suffix_kernel<<<dim3(48), dim3(64), 0, stream>>>(ts_raw, ts_suf);
    attn_kernel<<<dim3(48, 32), dim3(256), 0, stream>>>(qkv, vt, ts_suf, aout);
    gemm_kernel<false><<<dim3(6, 64), dim3(256), 0, stream>>>(aout, wTp, b_proj,
                                                              (void*)out, 8192, 768, 768);
}

// Round 4
// 198.893 us; speedup vs baseline: 1.6738x; 1.0489x over previous
//
#include <hip/hip_runtime.h>
#include <cstdint>

typedef unsigned short u16;
typedef __bf16 bf16;
typedef bf16 bf16x8 __attribute__((ext_vector_type(8)));
typedef u16 u16x4 __attribute__((ext_vector_type(4)));
typedef u16 u16x8 __attribute__((ext_vector_type(8)));
typedef float f32x4 __attribute__((ext_vector_type(4)));

__device__ __forceinline__ u16 f2b(float f) {
    return __builtin_bit_cast(u16, (bf16)f);
}
__device__ __forceinline__ float b2f(u16 u) {
    return __uint_as_float(((unsigned)u) << 16);
}
__device__ __forceinline__ void load_lds16(const void* g, void* l) {
    auto gp = reinterpret_cast<const __attribute__((address_space(1))) void*>(
        reinterpret_cast<uintptr_t>(g));
    auto lp = reinterpret_cast<__attribute__((address_space(3))) void*>(
        reinterpret_cast<uintptr_t>(l));
    __builtin_amdgcn_global_load_lds(gp, lp, 16, 0, 0);
}
__device__ __forceinline__ f32x4 mfma16(bf16x8 a, bf16x8 b, f32x4 c) {
    return __builtin_amdgcn_mfma_f32_16x16x32_bf16(a, b, c, 0, 0, 0);
}

// ---------------------------------------------------------------- convert x -> bf16
__global__ __launch_bounds__(256) void convx_kernel(const float* __restrict__ x,
                                                    u16* __restrict__ xb, int n4) {
    int i = blockIdx.x * blockDim.x + threadIdx.x;
    int stride = gridDim.x * blockDim.x;
    for (; i < n4; i += stride) {
        float4 v = ((const float4*)x)[i];
        u16x4 r;
        r[0] = f2b(v.x); r[1] = f2b(v.y); r[2] = f2b(v.z); r[3] = f2b(v.w);
        *(u16x4*)&xb[(size_t)i * 4] = r;
    }
}

// ------------------- combined transpose+convert for both weights: [K=768][N] f32 -> [N][768] bf16
__global__ __launch_bounds__(256) void wtrans2_kernel(const float* __restrict__ wa,
                                                      const float* __restrict__ wp,
                                                      u16* __restrict__ wTa,
                                                      u16* __restrict__ wTp) {
    __shared__ float tile[32][33];
    const int bx = blockIdx.x;
    const float* w;
    u16* wT;
    int N, n0;
    if (bx < 72) { w = wa; wT = wTa; N = 2304; n0 = bx * 32; }
    else         { w = wp; wT = wTp; N = 768;  n0 = (bx - 72) * 32; }
    const int K = 768;
    int tx = threadIdx.x, ty = threadIdx.y;  // (32, 8)
    int k0 = blockIdx.y * 32;
#pragma unroll
    for (int i = 0; i < 4; ++i)
        tile[ty + i * 8][tx] = w[(size_t)(k0 + ty + i * 8) * N + n0 + tx];
    __syncthreads();
#pragma unroll
    for (int i = 0; i < 4; ++i)
        wT[(size_t)(n0 + ty + i * 8) * K + k0 + tx] = f2b(tile[tx][ty + i * 8]);
}

// ---------------------------------------------------------------- GEMM: C[M][N] = A[M][K] * Bt[N][K]^T + bias
// 128x128 tile, 4 waves, 16x16x32 MFMA, gload_lds staging, XCD-aware block swizzle.
template <bool OUT_BF16>
__global__ __launch_bounds__(256, 3) void gemm_kernel(const u16* __restrict__ A,
                                                      const u16* __restrict__ Bt,
                                                      const float* __restrict__ bias,
                                                      void* __restrict__ out,
                                                      int M, int N, int K) {
    __shared__ __align__(16) u16 As[128 * 64];
    __shared__ __align__(16) u16 Bs[128 * 64];
    const int tid = threadIdx.x;
    const int wave = tid >> 6, lane = tid & 63;
    const int l15 = lane & 15, lg = lane >> 4;
    // XCD-aware swizzle (T1); nwg % 8 == 0 for both GEMMs here.
    const int gx = gridDim.x;
    const int nwg = gx * gridDim.y;
    const int lin = blockIdx.y * gx + blockIdx.x;
    const int swz = (lin & 7) * (nwg >> 3) + (lin >> 3);
    const int tm = (swz / gx) * 128, tn = (swz % gx) * 128;
    const int wr = (wave >> 1) * 64, wc = (wave & 1) * 64;

    f32x4 acc[4][4] = {};

    const int rbase = wave * 8 + (lane >> 3);
    const int sslot = (lane & 7) ^ (rbase & 7);
    const u16* gA = A + (size_t)(tm + rbase) * K + sslot * 8;
    const u16* gB = Bt + (size_t)(tn + rbase) * K + sslot * 8;
    u16* ldsA = As + (size_t)(wave * 8) * 64;
    u16* ldsB = Bs + (size_t)(wave * 8) * 64;

    for (int kt = 0; kt < K; kt += 64) {
#pragma unroll
        for (int i = 0; i < 4; ++i) {
            load_lds16(gA + (size_t)i * 32 * K + kt, ldsA + i * 32 * 64);
            load_lds16(gB + (size_t)i * 32 * K + kt, ldsB + i * 32 * 64);
        }
        __syncthreads();
#pragma unroll
        for (int kk = 0; kk < 64; kk += 32) {
            const int sb = kk >> 3;
            bf16x8 af[4], bfr[4];
#pragma unroll
            for (int m = 0; m < 4; ++m) {
                int row = wr + m * 16 + l15;
                af[m] = *(const bf16x8*)&As[row * 64 + (((sb + lg) ^ (row & 7))) * 8];
            }
#pragma unroll
            for (int n = 0; n < 4; ++n) {
                int row = wc + n * 16 + l15;
                bfr[n] = *(const bf16x8*)&Bs[row * 64 + (((sb + lg) ^ (row & 7))) * 8];
            }
#pragma unroll
            for (int m = 0; m < 4; ++m)
#pragma unroll
                for (int n = 0; n < 4; ++n)
                    acc[m][n] = mfma16(af[m], bfr[n], acc[m][n]);
        }
        __syncthreads();
    }

#pragma unroll
    for (int n = 0; n < 4; ++n) {
        int col = tn + wc + n * 16 + l15;
        float bv = bias[col];
#pragma unroll
        for (int m = 0; m < 4; ++m) {
            int row0 = tm + wr + m * 16 + lg * 4;
#pragma unroll
            for (int r = 0; r < 4; ++r) {
                float v = acc[m][n][r] + bv;
                if constexpr (OUT_BF16)
                    ((u16*)out)[(size_t)(row0 + r) * N + col] = f2b(v);
                else
                    ((float*)out)[(size_t)(row0 + r) * N + col] = v;
            }
        }
    }
}

// ---------------------------------------------------------------- V transpose + fused per-64-tile colsum
// qkv V-part -> vt[bh][d=64][s=2048]; ts_raw[bh][st][d] = sum_s V[st*64+s][d]
__global__ __launch_bounds__(256) void vtrans_kernel(const u16* __restrict__ qkv,
                                                     u16* __restrict__ vt,
                                                     float* __restrict__ ts_raw) {
    __shared__ __align__(16) u16 tile[64][72];
    __shared__ float red2[64][4];
    const int st = blockIdx.x, bh = blockIdx.y;
    const int b = bh / 12, h = bh % 12;
    const int t = threadIdx.x;
    const int sr = t >> 2, c4 = (t & 3) * 16;
    const u16* src = qkv + (size_t)(b * 2048 + st * 64 + sr) * 2304 + 1536 + h * 64 + c4;
    *(u16x8*)&tile[sr][c4] = *(const u16x8*)src;
    *(u16x8*)&tile[sr][c4 + 8] = *(const u16x8*)(src + 8);
    __syncthreads();
    const int dr = t >> 2, s4 = (t & 3) * 16;
    u16x8 w0, w1;
    float psum = 0.f;
#pragma unroll
    for (int j = 0; j < 8; ++j) {
        w0[j] = tile[s4 + j][dr];
        w1[j] = tile[s4 + 8 + j][dr];
        psum += b2f(w0[j]) + b2f(w1[j]);
    }
    u16* dst = vt + ((size_t)bh * 64 + dr) * 2048 + st * 64 + s4;
    *(u16x8*)dst = w0;
    *(u16x8*)(dst + 8) = w1;
    red2[dr][t & 3] = psum;
    __syncthreads();
    if (t < 64)
        ts_raw[((size_t)bh * 32 + st) * 64 + t] =
            red2[t][0] + red2[t][1] + red2[t][2] + red2[t][3];
}

// ---------------------------------------------------------------- attention (swapped-operand, defer-max, QBLK=128)
// grid (48 bh, 16 qtr), 256 thr (4 waves x 32 q-rows). KBLK=64, one barrier/iter,
// K/V double-buffered, suffix tail summed in-kernel from ts_raw.
__global__ __launch_bounds__(256, 3) void attn_kernel(const u16* __restrict__ qkv,
                                                      const u16* __restrict__ vt,
                                                      const float* __restrict__ ts_raw,
                                                      u16* __restrict__ aout) {
    __shared__ __align__(16) u16 Ks[2][64 * 64];
    __shared__ __align__(16) u16 Vs[2][64 * 64];   // transposed V: [d][k]
    __shared__ __align__(16) u16 Ps[128 * 64];     // P^T rows [q_local][k], wave-private rows
    const int bh = blockIdx.x;                     // bh fastest: same-bh blocks share XCD L2
    const int qt = 15 - blockIdx.y;                // longest-first dispatch
    const int b = bh / 12, h = bh % 12;
    const int tid = threadIdx.x, wave = tid >> 6, lane = tid & 63;
    const int l15 = lane & 15, lg = lane >> 4;
    const int q0 = qt * 128 + wave * 32;
    const size_t rowbase = (size_t)b * 2048;

    // Q fragments (B-operand): lane holds Q[q0+m*16+l15][ks*32 + lg*8 .. +8]
    bf16x8 qf[2][2];
#pragma unroll
    for (int m = 0; m < 2; ++m)
#pragma unroll
        for (int ks = 0; ks < 2; ++ks)
            qf[m][ks] = *(const bf16x8*)(qkv + (rowbase + q0 + m * 16 + l15) * 2304 +
                                         h * 64 + ks * 32 + lg * 8);

    f32x4 o[2][4] = {};       // O^T: lane holds O[q0+m*16+l15][d = dn*16 + lg*4 + r]
    float mrun = -1e30f;      // shared reference max (wave-global on rescale)
    float lrun[2] = {0.f, 0.f};

    // staging constants (gload_lds: linear LDS dest, pre-swizzled global source)
    const int rbase = wave * 8 + (lane >> 3);
    const int sslot = (lane & 7) ^ (rbase & 7);
    const u16* gK = qkv + (rowbase + rbase) * 2304 + 768 + h * 64 + sslot * 8;
    const u16* gV = vt + ((size_t)bh * 64 + rbase) * 2048 + sslot * 8;
    const int ldsoff = wave * 8 * 64;

    const int nkt = 2 * qt + 2;
#pragma unroll
    for (int i = 0; i < 2; ++i) {
        load_lds16(gK + (size_t)(i * 32) * 2304, &Ks[0][ldsoff + i * 32 * 64]);
        load_lds16(gV + (size_t)(i * 32) * 2048, &Vs[0][ldsoff + i * 32 * 64]);
    }

    for (int kt = 0; kt < nkt; ++kt) {
        __syncthreads();  // drains vmcnt: tile[cur] ready; prev-iter LDS reads done
        const int cur = kt & 1;
        if (kt + 1 < nkt) {
            const int nx = cur ^ 1;
#pragma unroll
            for (int i = 0; i < 2; ++i) {
                load_lds16(gK + ((size_t)(kt + 1) * 64 + i * 32) * 2304,
                           &Ks[nx][ldsoff + i * 32 * 64]);
                load_lds16(gV + (size_t)(i * 32) * 2048 + (kt + 1) * 64,
                           &Vs[nx][ldsoff + i * 32 * 64]);
            }
        }

        // S^T = K Q^T : lane gets S[k = kt*64 + n*16 + lg*4 + r][q = q0 + m*16 + l15]
        f32x4 sacc[2][4] = {};
        __builtin_amdgcn_s_setprio(1);
#pragma unroll
        for (int ks = 0; ks < 2; ++ks) {
#pragma unroll
            for (int n = 0; n < 4; ++n) {
                int row = n * 16 + l15;
                bf16x8 ak = *(const bf16x8*)&Ks[cur][row * 64 +
                                                     (((ks * 4 + lg) ^ (row & 7))) * 8];
                sacc[0][n] = mfma16(ak, qf[0][ks], sacc[0][n]);
                sacc[1][n] = mfma16(ak, qf[1][ks], sacc[1][n]);
            }
        }
        __builtin_amdgcn_s_setprio(0);

        // reference mask trick on the last two (diagonal-containing) tiles
        if (kt >= 2 * qt) {
#pragma unroll
            for (int m = 0; m < 2; ++m) {
                const int q = q0 + m * 16 + l15;
#pragma unroll
                for (int n = 0; n < 4; ++n)
#pragma unroll
                    for (int r = 0; r < 4; ++r) {
                        int k = kt * 64 + n * 16 + lg * 4 + r;
                        if (k > q) sacc[m][n][r] = 1e-9f;
                    }
            }
        }

        // defer-max: lane-local max over both rows; rescale only when it grows >THR
        float mx = sacc[0][0][0];
#pragma unroll
        for (int m = 0; m < 2; ++m)
#pragma unroll
            for (int n = 0; n < 4; ++n)
                mx = fmaxf(mx, fmaxf(fmaxf(sacc[m][n][0], sacc[m][n][1]),
                                     fmaxf(sacc[m][n][2], sacc[m][n][3])));
        if (__any(mx > mrun + 8.0f)) {
            float rm = fmaxf(mx, __shfl_xor(mx, 16));
            rm = fmaxf(rm, __shfl_xor(rm, 32));
            rm = fmaxf(rm, __shfl_xor(rm, 1));
            rm = fmaxf(rm, __shfl_xor(rm, 2));
            rm = fmaxf(rm, __shfl_xor(rm, 4));
            rm = fmaxf(rm, __shfl_xor(rm, 8));
            const float mnew = fmaxf(mrun, rm);
            const float alpha = __expf(mrun - mnew);
            mrun = mnew;
            lrun[0] *= alpha;
            lrun[1] *= alpha;
#pragma unroll
            for (int m = 0; m < 2; ++m)
#pragma unroll
                for (int dn = 0; dn < 4; ++dn) o[m][dn] *= alpha;
        }

        // P = exp(S - mrun) (bounded by e^8), pack bf16, write wave-private LDS rows
#pragma unroll
        for (int m = 0; m < 2; ++m) {
            const int prow = wave * 32 + m * 16 + l15;
#pragma unroll
            for (int n = 0; n < 4; ++n) {
                u16x4 pk;
#pragma unroll
                for (int r = 0; r < 4; ++r) {
                    float p = __expf(sacc[m][n][r] - mrun);
                    lrun[m] += p;
                    pk[r] = f2b(p);
                }
                int slot = n * 2 + (lg >> 1);
                *(u16x4*)&Ps[prow * 64 + ((slot ^ (prow & 7))) * 8 + (lg & 1) * 4] = pk;
            }
        }

        // O^T += V^T P^T
        __builtin_amdgcn_s_setprio(1);
#pragma unroll
        for (int ks = 0; ks < 2; ++ks) {
            const int prow0 = wave * 32 + l15;
            bf16x8 bp0 = *(const bf16x8*)&Ps[prow0 * 64 +
                                             (((ks * 4 + lg) ^ (prow0 & 7))) * 8];
            bf16x8 bp1 = *(const bf16x8*)&Ps[(prow0 + 16) * 64 +
                                             (((ks * 4 + lg) ^ (prow0 & 7))) * 8];
#pragma unroll
            for (int dn = 0; dn < 4; ++dn) {
                int row = dn * 16 + l15;
                bf16x8 av = *(const bf16x8*)&Vs[cur][row * 64 +
                                                     (((ks * 4 + lg) ^ (row & 7))) * 8];
                o[0][dn] = mfma16(av, bp0, o[0][dn]);
                o[1][dn] = mfma16(av, bp1, o[1][dn]);
            }
        }
        __builtin_amdgcn_s_setprio(0);
    }

    // fold per-lane l across the 4 lane-groups of each row (once, not per tile)
#pragma unroll
    for (int m = 0; m < 2; ++m) {
        lrun[m] += __shfl_xor(lrun[m], 16);
        lrun[m] += __shfl_xor(lrun[m], 32);
    }

    // analytic future tail: all k >= (qt+1)*128 carry score exactly 1e-9
    if (qt < 15) {
        const float nf = (float)((15 - qt) * 128);
        const float mnew = fmaxf(mrun, 1e-9f);
        const float a = __expf(mrun - mnew);
        const float c = __expf(1e-9f - mnew);
        lrun[0] = lrun[0] * a + nf * c;
        lrun[1] = lrun[1] * a + nf * c;
        f32x4 suf[4] = {};
        for (int t = 2 * qt + 2; t < 32; ++t) {
            const float* sp = ts_raw + ((size_t)bh * 32 + t) * 64;
#pragma unroll
            for (int dn = 0; dn < 4; ++dn)
                suf[dn] += *(const f32x4*)&sp[dn * 16 + lg * 4];
        }
#pragma unroll
        for (int m = 0; m < 2; ++m)
#pragma unroll
            for (int dn = 0; dn < 4; ++dn)
                o[m][dn] = o[m][dn] * a + suf[dn] * c;
    }

    // normalize + store merged-head layout [B*S][768] bf16
#pragma unroll
    for (int m = 0; m < 2; ++m) {
        const float inv = 1.f / lrun[m];
        const size_t row = rowbase + q0 + m * 16 + l15;
#pragma unroll
        for (int dn = 0; dn < 4; ++dn) {
            u16x4 st;
#pragma unroll
            for (int r = 0; r < 4; ++r) st[r] = f2b(o[m][dn][r] * inv);
            *(u16x4*)&aout[row * 768 + h * 64 + dn * 16 + lg * 4] = st;
        }
    }
}

// ---------------------------------------------------------------- launch
extern "C" void kernel_launch(void* const* d_in, const int* in_sizes, int n_in,
                              void* d_out, int out_size, void* d_ws, size_t ws_size,
                              hipStream_t stream) {
    const float* x      = (const float*)d_in[0];
    const float* w_attn = (const float*)d_in[1];
    const float* b_attn = (const float*)d_in[2];
    const float* w_proj = (const float*)d_in[3];
    const float* b_proj = (const float*)d_in[4];
    float* out = (float*)d_out;
    char* ws = (char*)d_ws;

    u16* xb      = (u16*)(ws + 0);          // 8192*768   bf16 = 12,582,912 B
    u16* wTa     = (u16*)(ws + 12582912);   // 2304*768   bf16 =  3,538,944 B
    u16* wTp     = (u16*)(ws + 16121856);   //  768*768   bf16 =  1,179,648 B
    u16* qkv     = (u16*)(ws + 17301504);   // 8192*2304  bf16 = 37,748,736 B
    u16* vt      = (u16*)(ws + 55050240);   // 48*64*2048 bf16 = 12,582,912 B
    u16* aout    = (u16*)(ws + 67633152);   // 8192*768   bf16 = 12,582,912 B
    // ts buffer reuses the xb region (xb's last consumer is gemm1, which runs earlier)
    float* ts_raw = (float*)(ws + 0);       // 48*32*64 f32 = 393,216 B (aliases xb)

    convx_kernel<<<dim3(2048), dim3(256), 0, stream>>>(x, xb, 8192 * 768 / 4);
    wtrans2_kernel<<<dim3(96, 24), dim3(32, 8), 0, stream>>>(w_attn, w_proj, wTa, wTp);
    gemm_kernel<true><<<dim3(18, 64), dim3(256), 0, stream>>>(xb, wTa, b_attn,
                                                              (void*)qkv, 8192, 2304, 768);
    vtrans_kernel<<<dim3(32, 48), dim3(256), 0, stream>>>(qkv, vt, ts_raw);
    attn_kernel<<<dim3(48, 16), dim3(256), 0, stream>>>(qkv, vt, ts_raw, aout);
    gemm_kernel<false><<<dim3(6, 64), dim3(256), 0, stream>>>(aout, wTp, b_proj,
                                                              (void*)out, 8192, 768, 768);
}